// Round 15
// baseline (345.229 us; speedup 1.0000x reference)
//
#include <hip/hip_runtime.h>

#define NN 50000
#define EE 300000
#define DD 256
#define RR 3
#define NPAD 50048            // 782 * 64
#define GS 64                 // split-K slices for G
#define SCT (RR * NN)         // 150000
#define SCB 1024
#define SNB ((SCT + SCB - 1) / SCB)  // 147
#define TBLK 3128             // transpose blocks in prep_tc (782*4)
#define WBLK 2560             // weight-copy blocks in prep_tc
#define CBLK 512              // count blocks in prep_tc

using bf16x8 = __attribute__((ext_vector_type(8))) short;
using f32x4  = __attribute__((ext_vector_type(4))) float;

__device__ __forceinline__ float bf2f(unsigned short u) {
    return __uint_as_float(((unsigned)u) << 16);
}
__device__ __forceinline__ unsigned short f2bf(float f) {
    unsigned u = __float_as_uint(f);
    return (unsigned short)((u + 0x7fffu + ((u >> 16) & 1u)) >> 16);
}
__device__ __forceinline__ void gload_lds16(const void* g, void* l) {
    __builtin_amdgcn_global_load_lds(
        (const __attribute__((address_space(1))) unsigned int*)g,
        (__attribute__((address_space(3))) unsigned int*)l, 16, 0, 0);
}

// ---------------------------------------------------------------------------
// Merged: x transpose/convert + weight bf16 copies + degree counts.
__global__ __launch_bounds__(256) void prep_tc(
    const float* __restrict__ x, const float* __restrict__ Wq,
    const float* __restrict__ Wk, const float* __restrict__ Wv,
    const float* __restrict__ Whp,
    unsigned short* __restrict__ xb, unsigned short* __restrict__ xT,
    unsigned short* __restrict__ Wqb, unsigned short* __restrict__ Wkb,
    unsigned short* __restrict__ Wvb, unsigned short* __restrict__ WhpT,
    const int* __restrict__ erow, const int* __restrict__ ecol,
    const int* __restrict__ etype, int* __restrict__ c_in,
    int* __restrict__ c_out, int* __restrict__ nr)
{
    const int tid = threadIdx.x;
    if (blockIdx.x < TBLK) {
        __shared__ unsigned short t[64][66];
        const int tb = blockIdx.x;
        const int n0 = (tb % 782) * 64, i0 = (tb / 782) * 64;
        const int nl = tid >> 2, c0 = (tid & 3) * 16;
        unsigned short vb[16];
        int n = n0 + nl;
        if (n < NN) {
            const float* src = x + (size_t)n * DD + i0 + c0;
#pragma unroll
            for (int q = 0; q < 16; q += 4) {
                float4 v = *(const float4*)(src + q);
                vb[q] = f2bf(v.x); vb[q + 1] = f2bf(v.y);
                vb[q + 2] = f2bf(v.z); vb[q + 3] = f2bf(v.w);
            }
#pragma unroll
            for (int q = 0; q < 16; q += 4)
                *(ushort4*)(xb + (size_t)n * DD + i0 + c0 + q) =
                    make_ushort4(vb[q], vb[q + 1], vb[q + 2], vb[q + 3]);
        } else {
#pragma unroll
            for (int q = 0; q < 16; q++) vb[q] = 0;
        }
#pragma unroll
        for (int q = 0; q < 16; q++) t[nl][c0 + q] = vb[q];
        __syncthreads();
        const int il = tid >> 2, nc0 = (tid & 3) * 16;
        unsigned short ob[16];
#pragma unroll
        for (int q = 0; q < 16; q++) ob[q] = t[nc0 + q][il];
#pragma unroll
        for (int q = 0; q < 16; q += 4)
            *(ushort4*)(xT + (size_t)(i0 + il) * NPAD + n0 + nc0 + q) =
                make_ushort4(ob[q], ob[q + 1], ob[q + 2], ob[q + 3]);
    } else if (blockIdx.x < TBLK + WBLK) {
        int t = (blockIdx.x - TBLK) * 256 + tid;
        int slot = t >> 16, o = t & 65535;
        int a = o >> 8, b = o & 255;
        if (slot < 3)       Wqb[(size_t)slot * 65536 + o] = f2bf(Wq[(size_t)slot * 65536 + o]);
        else if (slot < 6)  Wkb[(size_t)(slot - 3) * 65536 + o] = f2bf(Wk[(size_t)(slot - 3) * 65536 + o]);
        else if (slot < 9)  Wvb[(size_t)(slot - 6) * 65536 + o] = f2bf(Wv[(size_t)(slot - 6) * 65536 + o]);
        else if (slot == 9) WhpT[o] = f2bf(Whp[b * 256 + a]);
    } else {
        __shared__ int lnr[RR];
        if (tid < RR) lnr[tid] = 0;
        __syncthreads();
        int cb = blockIdx.x - (TBLK + WBLK);
        for (int e = cb * 256 + tid; e < EE; e += CBLK * 256) {
            int t = etype[e];
            atomicAdd(&c_out[t * NN + erow[e]], 1);
            atomicAdd(&c_in[t * NN + ecol[e]], 1);
            atomicAdd(&lnr[t], 1);
        }
        __syncthreads();
        if (tid < RR) atomicAdd(&nr[tid], lnr[tid]);
    }
}

// ---------------------------------------------------------------------------
// Merged: blocks 0..SNB-1 scan_reduce; SNB..SNB+255 xw; rest wbf conversion.
__global__ __launch_bounds__(256) void prep2(
    const int* __restrict__ c_out, int* __restrict__ bsum,
    const unsigned short* __restrict__ xT, const int* __restrict__ c_in,
    float* __restrict__ xw, unsigned short* __restrict__ wbf)
{
    const int tid = threadIdx.x;
    if (blockIdx.x < SNB) {
        __shared__ int ws[4];
        const int b = blockIdx.x;
        const int i = b * SCB + tid * 4;
        int s = 0;
        if (i < SCT) {
            int4 v = *(const int4*)(c_out + i);
            s = v.x + v.y + v.z + v.w;
        }
#pragma unroll
        for (int off = 32; off; off >>= 1) s += __shfl_down(s, off, 64);
        if ((tid & 63) == 0) ws[tid >> 6] = s;
        __syncthreads();
        if (tid == 0) bsum[b] = ws[0] + ws[1] + ws[2] + ws[3];
    } else if (blockIdx.x < SNB + 256) {
        __shared__ float red[3][4];
        const int i = blockIdx.x - SNB;
        float a0 = 0.f, a1 = 0.f, a2 = 0.f;
        for (int n = tid * 4; n < NN; n += 1024) {
            ushort4 xv = *(const ushort4*)(xT + (size_t)i * NPAD + n);
            int4 w0 = *(const int4*)(c_in + n);
            int4 w1 = *(const int4*)(c_in + NN + n);
            int4 w2 = *(const int4*)(c_in + 2 * NN + n);
            float f0 = bf2f(xv.x), f1 = bf2f(xv.y), f2 = bf2f(xv.z), f3 = bf2f(xv.w);
            a0 += f0 * w0.x + f1 * w0.y + f2 * w0.z + f3 * w0.w;
            a1 += f0 * w1.x + f1 * w1.y + f2 * w1.z + f3 * w1.w;
            a2 += f0 * w2.x + f1 * w2.y + f2 * w2.z + f3 * w2.w;
        }
#pragma unroll
        for (int off = 32; off; off >>= 1) {
            a0 += __shfl_down(a0, off, 64);
            a1 += __shfl_down(a1, off, 64);
            a2 += __shfl_down(a2, off, 64);
        }
        if ((tid & 63) == 0) {
            red[0][tid >> 6] = a0; red[1][tid >> 6] = a1; red[2][tid >> 6] = a2;
        }
        __syncthreads();
        if (tid < 3)
            xw[tid * 256 + i] = red[tid][0] + red[tid][1] + red[tid][2] + red[tid][3];
    } else {
        int t = (blockIdx.x - SNB - 256) * 256 + tid;
        if (t < 3 * NPAD) {
            int r = t / NPAD, n = t % NPAD;
            wbf[t] = f2bf(n < NN ? (float)c_in[r * NN + n] : 0.f);
        }
    }
}

// ---------------------------------------------------------------------------
// scan_bot with top-scan absorbed: each block scans bsum locally.
__global__ __launch_bounds__(256) void scan_bot(
    const int* __restrict__ cnt, const int* __restrict__ bsum,
    int* __restrict__ off, int* __restrict__ cur)
{
    __shared__ int bs[256], loc[256];
    const int b = blockIdx.x, tid = threadIdx.x;
    int v = tid < SNB ? bsum[tid] : 0;
    bs[tid] = v;
    __syncthreads();
    for (int d = 1; d < 256; d <<= 1) {
        int t = (tid >= d) ? bs[tid - d] : 0;
        __syncthreads();
        bs[tid] += t;
        __syncthreads();
    }
    const int myboff = b ? bs[b - 1] : 0;
    const int total = bs[255];
    const int i = b * SCB + tid * 4;
    int4 vv = make_int4(0, 0, 0, 0);
    if (i < SCT) vv = *(const int4*)(cnt + i);
    int s = vv.x + vv.y + vv.z + vv.w;
    loc[tid] = s;
    __syncthreads();
    for (int d = 1; d < 256; d <<= 1) {
        int t = (tid >= d) ? loc[tid - d] : 0;
        __syncthreads();
        loc[tid] += t;
        __syncthreads();
    }
    if (i < SCT) {
        int pre = myboff + (tid ? loc[tid - 1] : 0);
        int4 o;
        o.x = pre;
        o.y = pre + vv.x;
        o.z = pre + vv.x + vv.y;
        o.w = pre + vv.x + vv.y + vv.z;
        *(int4*)(off + i) = o;
        *(int4*)(cur + i) = o;
    }
    if (b == 0 && tid == 0) off[SCT] = total;
}

// Bucket-fill: sorted_col grouped by key (t*NN+row).
__global__ __launch_bounds__(256) void fill_kernel(
    const int* __restrict__ erow, const int* __restrict__ ecol,
    const int* __restrict__ etype, int* __restrict__ cur,
    int* __restrict__ scol)
{
    int e = blockIdx.x * 256 + threadIdx.x;
    if (e < EE) {
        int key = etype[e] * NN + erow[e];
        int p = atomicAdd(&cur[key], 1);
        scol[p] = ecol[e];
    }
}

// ---------------------------------------------------------------------------
// G partials: Gp[z][tile][r][128*128] += xT(w-scaled) @ xT^T over node chunk z
__global__ __launch_bounds__(512) void g_kernel(
    const unsigned short* __restrict__ xT, const unsigned short* __restrict__ wbf,
    float* __restrict__ Gp)
{
    __shared__ __align__(16) char ldsA[16384];
    __shared__ __align__(16) char ldsB[16384];
    const int tid = threadIdx.x, lane = tid & 63, wid = tid >> 6;
    const int wr = wid >> 1, wc = wid & 1;
    const int i0 = blockIdx.x * 128, j0 = blockIdx.y * 128;
    const int TPZ = (NPAD / 64 + GS - 1) / GS;
    const int kt0 = blockIdx.z * TPZ;
    const int kt1 = min(NPAD / 64, kt0 + TPZ);

    f32x4 acc[3][2][4];
#pragma unroll
    for (int r = 0; r < 3; r++)
#pragma unroll
        for (int m = 0; m < 2; m++)
#pragma unroll
            for (int n = 0; n < 4; n++) acc[r][m][n] = (f32x4){0.f, 0.f, 0.f, 0.f};

    for (int kt = kt0; kt < kt1; kt++) {
        const int kbyte = kt * 128;
#pragma unroll
        for (int is = 0; is < 2; is++) {
            int lb = is * 8192 + wid * 1024;
            int d = lb + lane * 16;
            int row = d >> 7;
            int sc_ = (d & 127) ^ ((row & 7) << 4);
            gload_lds16((const char*)xT + (size_t)(i0 + row) * (NPAD * 2) + kbyte + sc_, ldsA + lb);
            gload_lds16((const char*)xT + (size_t)(j0 + row) * (NPAD * 2) + kbyte + sc_, ldsB + lb);
        }
        __syncthreads();
#pragma unroll
        for (int kk = 0; kk < 2; kk++) {
            const int cb = kk * 64 + ((lane >> 4) << 4);
            bf16x8 bfr[4];
#pragma unroll
            for (int n = 0; n < 4; n++) {
                int rn = wc * 64 + n * 16 + (lane & 15);
                bfr[n] = *(const bf16x8*)(ldsB + rn * 128 + (cb ^ ((rn & 7) << 4)));
            }
            float au[2][8];
#pragma unroll
            for (int m = 0; m < 2; m++) {
                int row = wr * 32 + m * 16 + (lane & 15);
                bf16x8 ar = *(const bf16x8*)(ldsA + row * 128 + (cb ^ ((row & 7) << 4)));
#pragma unroll
                for (int q = 0; q < 8; q++) au[m][q] = bf2f((unsigned short)ar[q]);
            }
            const int nb = kt * 64 + kk * 32 + ((lane >> 4) << 3);
#pragma unroll
            for (int r = 0; r < 3; r++) {
                bf16x8 wv = *(const bf16x8*)(wbf + (size_t)r * NPAD + nb);
                float wf[8];
#pragma unroll
                for (int q = 0; q < 8; q++) wf[q] = bf2f((unsigned short)wv[q]);
                bf16x8 am[2];
#pragma unroll
                for (int m = 0; m < 2; m++)
#pragma unroll
                    for (int q = 0; q < 8; q++)
                        am[m][q] = (short)f2bf(au[m][q] * wf[q]);
#pragma unroll
                for (int m = 0; m < 2; m++)
#pragma unroll
                    for (int n = 0; n < 4; n++)
                        acc[r][m][n] = __builtin_amdgcn_mfma_f32_16x16x32_bf16(
                            am[m], bfr[n], acc[r][m][n], 0, 0, 0);
            }
        }
        __syncthreads();
    }
    float* base = Gp + ((size_t)blockIdx.z * 4 + blockIdx.x * 2 + blockIdx.y) * 3 * 16384;
#pragma unroll
    for (int r = 0; r < 3; r++)
#pragma unroll
        for (int m = 0; m < 2; m++)
#pragma unroll
            for (int n = 0; n < 4; n++) {
                int col = wc * 64 + n * 16 + (lane & 15);
                int rw0 = wr * 32 + m * 16 + ((lane >> 4) << 2);
#pragma unroll
                for (int reg = 0; reg < 4; reg++)
                    base[r * 16384 + (rw0 + reg) * 128 + col] = acc[r][m][n][reg];
            }
}

// ---------------------------------------------------------------------------
// Merged: blocks 0..767 reduce Gp over z -> Gb (bf16);
//         blocks 768..959: tv[r][row] = dot(M1[r] row, xw[r])   (matvec)
__global__ __launch_bounds__(256) void gred_mv(
    const float* __restrict__ Gp, unsigned short* __restrict__ Gb,
    const unsigned short* __restrict__ M1, const float* __restrict__ xw,
    float* __restrict__ tv)
{
    const int tid = threadIdx.x;
    if (blockIdx.x < 768) {
        int gid = blockIdx.x * 256 + tid;
        int t = gid >> 14, rem = gid & 16383;
        int r = t % 3, tile = t / 3;
        float s = 0.f;
        for (int z = 0; z < GS; z++)
            s += Gp[(size_t)z * 196608 + ((size_t)tile * 3 + r) * 16384 + rem];
        int i = (tile >> 1) * 128 + (rem >> 7);
        int j = (tile & 1) * 128 + (rem & 127);
        Gb[(size_t)r * 65536 + i * 256 + j] = f2bf(s);
    } else {
        __shared__ float vs[256];
        const int b = blockIdx.x - 768;
        const int r = b >> 6, rb = (b & 63) * 4;
        vs[tid] = xw[r * 256 + tid];
        __syncthreads();
        const int wid = tid >> 6, lane = tid & 63;
        const int row = rb + wid;
        ushort4 m4 = *(const ushort4*)(M1 + (size_t)r * 65536 + row * 256 + lane * 4);
        float s = bf2f(m4.x) * vs[lane * 4] + bf2f(m4.y) * vs[lane * 4 + 1] +
                  bf2f(m4.z) * vs[lane * 4 + 2] + bf2f(m4.w) * vs[lane * 4 + 3];
#pragma unroll
        for (int off = 32; off; off >>= 1) s += __shfl_down(s, off, 64);
        if (lane == 0) tv[r * 256 + row] = s;
    }
}

// ---------------------------------------------------------------------------
// One wave per node, qs fused, interleaved 3-stream segment walk.
__global__ __launch_bounds__(256) void gather_kernel(
    const unsigned short* __restrict__ xb, const int* __restrict__ scol,
    const int* __restrict__ off, const float* __restrict__ tv,
    const int* __restrict__ c_out, const int* __restrict__ nr,
    unsigned short* __restrict__ Ascat, float* __restrict__ s2g)
{
    __shared__ float ts[768];
    __shared__ float nrs[RR];
    const int tid = threadIdx.x;
    for (int k = tid; k < 768; k += 256) ts[k] = tv[k];
    if (tid < RR) nrs[tid] = (float)nr[tid];
    __syncthreads();
    const int wid = tid >> 6, lane = tid & 63;
    const int n = blockIdx.x * 4 + wid;
    if (n >= NN) return;
    ushort4 xv = *(const ushort4*)(xb + (size_t)n * DD + lane * 4);
    float xf[4] = {bf2f(xv.x), bf2f(xv.y), bf2f(xv.z), bf2f(xv.w)};
    float dots[RR];
#pragma unroll
    for (int t = 0; t < RR; t++) {
        float s = xf[0] * ts[t * 256 + lane * 4] + xf[1] * ts[t * 256 + lane * 4 + 1] +
                  xf[2] * ts[t * 256 + lane * 4 + 2] + xf[3] * ts[t * 256 + lane * 4 + 3];
#pragma unroll
        for (int o = 32; o; o >>= 1) s += __shfl_xor(s, o, 64);
        dots[t] = s;
    }
    int i0 = off[0 * NN + n], e0 = off[0 * NN + n + 1];
    int i1 = off[1 * NN + n], e1 = off[1 * NN + n + 1];
    int i2 = off[2 * NN + n], e2 = off[2 * NN + n + 1];
    float a0[4] = {0.f, 0.f, 0.f, 0.f};
    float a1[4] = {0.f, 0.f, 0.f, 0.f};
    float a2[4] = {0.f, 0.f, 0.f, 0.f};
    while (i0 < e0 || i1 < e1 || i2 < e2) {
        bool h0 = i0 < e0, h1 = i1 < e1, h2 = i2 < e2;
        ushort4 v0, v1, v2;
        if (h0) { int c = scol[i0]; v0 = *(const ushort4*)(xb + (size_t)c * DD + lane * 4); }
        if (h1) { int c = scol[i1]; v1 = *(const ushort4*)(xb + (size_t)c * DD + lane * 4); }
        if (h2) { int c = scol[i2]; v2 = *(const ushort4*)(xb + (size_t)c * DD + lane * 4); }
        if (h0) { a0[0] += bf2f(v0.x); a0[1] += bf2f(v0.y);
                  a0[2] += bf2f(v0.z); a0[3] += bf2f(v0.w); i0++; }
        if (h1) { a1[0] += bf2f(v1.x); a1[1] += bf2f(v1.y);
                  a1[2] += bf2f(v1.z); a1[3] += bf2f(v1.w); i1++; }
        if (h2) { a2[0] += bf2f(v2.x); a2[1] += bf2f(v2.y);
                  a2[2] += bf2f(v2.z); a2[3] += bf2f(v2.w); i2++; }
    }
    float* accs[3] = {a0, a1, a2};
#pragma unroll
    for (int t = 0; t < RR; t++) {
        float nrf = nrs[t];
        float denom = dots[t] + nrf;
        if (lane == 0) {
            int cnt = c_out[t * NN + n];
            s2g[(size_t)t * NN + n] = cnt ? (float)cnt / denom : 0.f;
        }
        float s1 = nrf / denom;
        float* a = accs[t];
        ushort4 o2;
        o2.x = f2bf(s1 * a[0]); o2.y = f2bf(s1 * a[1]);
        o2.z = f2bf(s1 * a[2]); o2.w = f2bf(s1 * a[3]);
        *(ushort4*)(Ascat + (size_t)n * 768 + t * 256 + lane * 4) = o2;
    }
}

// ---------------------------------------------------------------------------
// Small MFMA NT GEMM (for 256x256 weight products)
template <int MODE, int SWZ>
__global__ __launch_bounds__(256) void gemm_nt(
    const unsigned short* __restrict__ A, int lda,
    const unsigned short* __restrict__ B, int ldb,
    void* __restrict__ Cv, int ldc, int M, int KK,
    size_t sa, size_t sb, size_t sc)
{
    A += (size_t)blockIdx.z * sa;
    B += (size_t)blockIdx.z * sb;
    __shared__ __align__(16) char ldsA[16384];
    __shared__ __align__(16) char ldsB[16384];
    const int tid = threadIdx.x, lane = tid & 63, wid = tid >> 6;
    const int wr = wid >> 1, wc = wid & 1;
    int bx = blockIdx.x;
    if (SWZ) {
        int nwg = gridDim.x, q = nwg >> 3, rem = nwg & 7;
        int xcd = bx & 7, idx = bx >> 3;
        bx = (xcd < rem ? xcd * (q + 1) : rem * (q + 1) + (xcd - rem) * q) + idx;
    }
    const int row0 = bx * 128, col0 = blockIdx.y * 128;

    f32x4 acc[4][4];
#pragma unroll
    for (int m = 0; m < 4; m++)
#pragma unroll
        for (int n = 0; n < 4; n++) acc[m][n] = (f32x4){0.f, 0.f, 0.f, 0.f};

    for (int k0 = 0; k0 < KK; k0 += 64) {
#pragma unroll
        for (int is = 0; is < 4; is++) {
            int lb = is * 4096 + wid * 1024;
            int d = lb + lane * 16;
            int row = d >> 7;
            int sc_ = (d & 127) ^ ((row & 7) << 4);
            int gr = row0 + row; gr = gr < M ? gr : M - 1;
            gload_lds16((const char*)(A + (size_t)gr * lda + k0) + sc_, ldsA + lb);
            int rn = col0 + row;
            gload_lds16((const char*)(B + (size_t)rn * ldb + k0) + sc_, ldsB + lb);
        }
        __syncthreads();
#pragma unroll
        for (int kk = 0; kk < 2; kk++) {
            bf16x8 af[4], bf_[4];
            const int cb = kk * 64 + ((lane >> 4) << 4);
#pragma unroll
            for (int m = 0; m < 4; m++) {
                int row = wr * 64 + m * 16 + (lane & 15);
                af[m] = *(const bf16x8*)(ldsA + row * 128 + (cb ^ ((row & 7) << 4)));
                int rn = wc * 64 + m * 16 + (lane & 15);
                bf_[m] = *(const bf16x8*)(ldsB + rn * 128 + (cb ^ ((rn & 7) << 4)));
            }
#pragma unroll
            for (int m = 0; m < 4; m++)
#pragma unroll
                for (int n = 0; n < 4; n++)
                    acc[m][n] = __builtin_amdgcn_mfma_f32_16x16x32_bf16(
                        af[m], bf_[n], acc[m][n], 0, 0, 0);
        }
        __syncthreads();
    }

#pragma unroll
    for (int m = 0; m < 4; m++) {
#pragma unroll
        for (int reg = 0; reg < 4; reg++) {
            int r = row0 + wr * 64 + m * 16 + ((lane >> 4) << 2) + reg;
            if (r >= M) continue;
#pragma unroll
            for (int n = 0; n < 4; n++) {
                int c = col0 + wc * 64 + n * 16 + (lane & 15);
                float v = acc[m][n][reg];
                if (MODE == 0)
                    ((unsigned short*)Cv)[(size_t)blockIdx.z * sc + (size_t)r * ldc + c] = f2bf(v);
                else
                    ((float*)Cv)[(size_t)blockIdx.z * sc + (size_t)r * ldc + c] = v;
            }
        }
    }
}

// ---------------------------------------------------------------------------
// Final fused GEMM: out = Σ_r diag(s2_r)(xb@Bnum_r^T) + Ascat@Bsc^T
// Depth-2 prefetch, 3 LDS buffers, counted vmcnt(6) barriers (T4): the 6
// newest loads (tile t+2) stay in flight across each barrier; only tile t+1
// (a full step old) is drained.
__global__ __launch_bounds__(512) void gemm_big(
    const unsigned short* __restrict__ Xb, const unsigned short* __restrict__ As,
    const unsigned short* __restrict__ Bm, const float* __restrict__ s2g,
    float* __restrict__ C, int M)
{
    extern __shared__ __align__(16) char lds[];
    char* ldsA = lds;                      // 3 x 16384
    char* ldsB = lds + 49152;              // 3 x 32768
    float* s2l = (float*)(lds + 147456);   // 384 floats
    const int tid = threadIdx.x, lane = tid & 63, wid = tid >> 6;
    const int wr = wid >> 2, wc = wid & 3;
    int bx = blockIdx.x;
    {
        int nwg = gridDim.x, q = nwg >> 3, rem = nwg & 7;
        int xcd = bx & 7, idx = bx >> 3;
        bx = (xcd < rem ? xcd * (q + 1) : rem * (q + 1) + (xcd - rem) * q) + idx;
    }
    const int row0 = bx * 128;

    if (tid < 384) {
        int rsel = tid >> 7, rr = tid & 127;
        int gr = row0 + rr; gr = gr < M ? gr : M - 1;
        s2l[tid] = s2g[(size_t)rsel * NN + gr];
    }

    f32x4 accO[4][4], acc[4][4];
#pragma unroll
    for (int m = 0; m < 4; m++)
#pragma unroll
        for (int n = 0; n < 4; n++) {
            accO[m][n] = (f32x4){0.f, 0.f, 0.f, 0.f};
            acc[m][n]  = (f32x4){0.f, 0.f, 0.f, 0.f};
        }

    // STAGE(buf, j): stage K-step j. A: j<12 from Xb k=(j&3)*64; else from As
    // k=(j-12)*64. B: k=j*64. 6 gload_lds per thread per call.
#define STAGE(buf, j)                                                          \
    {                                                                          \
        const unsigned short* Asrc_ = (j) < 12 ? Xb : As;                      \
        const int ldaE_ = (j) < 12 ? 256 : 768;                                \
        const int kA_ = (j) < 12 ? ((j) & 3) * 64 : ((j) - 12) * 64;           \
        const int kB_ = (j) * 64;                                              \
        _Pragma("unroll")                                                      \
        for (int is = 0; is < 2; is++) {                                       \
            int lb = is * 8192 + wid * 1024;                                   \
            int d = lb + lane * 16;                                            \
            int row = d >> 7;                                                  \
            int sc_ = (d & 127) ^ ((row & 7) << 4);                            \
            int gr = row0 + row; gr = gr < M ? gr : M - 1;                     \
            gload_lds16((const char*)(Asrc_ + (size_t)gr * ldaE_ + kA_) + sc_, \
                        ldsA + (buf) * 16384 + lb);                            \
        }                                                                      \
        _Pragma("unroll")                                                      \
        for (int is = 0; is < 4; is++) {                                       \
            int lb = is * 8192 + wid * 1024;                                   \
            int d = lb + lane * 16;                                            \
            int row = d >> 7;                                                  \
            int sc_ = (d & 127) ^ ((row & 7) << 4);                            \
            gload_lds16((const char*)(Bm + (size_t)row * 1536 + kB_) + sc_,    \
                        ldsB + (buf) * 32768 + lb);                            \
        }                                                                      \
    }

#define MFMA_STEP(buf, ACC)                                                    \
    { const char* bA = ldsA + (buf) * 16384;                                   \
      const char* bB = ldsB + (buf) * 32768;                                   \
      _Pragma("unroll")                                                        \
      for (int kk = 0; kk < 2; kk++) {                                         \
          bf16x8 af[4], bf_[4];                                                \
          const int cb = kk * 64 + ((lane >> 4) << 4);                         \
          _Pragma("unroll")                                                    \
          for (int m = 0; m < 4; m++) {                                        \
              int row = wr * 64 + m * 16 + (lane & 15);                        \
              af[m] = *(const bf16x8*)(bA + row * 128 + (cb ^ ((row & 7) << 4)));\
              int rn = wc * 64 + m * 16 + (lane & 15);                         \
              bf_[m] = *(const bf16x8*)(bB + rn * 128 + (cb ^ ((rn & 7) << 4)));\
          }                                                                    \
          _Pragma("unroll")                                                    \
          for (int m = 0; m < 4; m++)                                          \
              _Pragma("unroll")                                                \
              for (int n = 0; n < 4; n++)                                      \
                  ACC[m][n] = __builtin_amdgcn_mfma_f32_16x16x32_bf16(         \
                      af[m], bf_[n], ACC[m][n], 0, 0, 0); } }

    STAGE(0, 0);
    STAGE(1, 1);
    // drain tile-0 loads (oldest 6 of 12) + the s2l ds_writes; tile-1 stays in flight
    asm volatile("s_waitcnt vmcnt(6) lgkmcnt(0)" ::: "memory");
    __builtin_amdgcn_s_barrier();
    asm volatile("" ::: "memory");

    for (int t = 0; t < 24; t++) {
        if (t + 2 < 24) STAGE((t + 2) % 3, t + 2);
        if (t < 12) { MFMA_STEP(t % 3, acc); }
        else        { MFMA_STEP(t % 3, accO); }
        // drain tile t+1 (oldest); keep tile t+2's 6 loads in flight
        if (t < 22) asm volatile("s_waitcnt vmcnt(6)" ::: "memory");
        else        asm volatile("s_waitcnt vmcnt(0)" ::: "memory");
        __builtin_amdgcn_s_barrier();
        asm volatile("" ::: "memory");
        if (t < 12 && (t & 3) == 3) {
            int pp = t >> 2;
#pragma unroll
            for (int m = 0; m < 4; m++) {
                f32x4 sv = *(const f32x4*)&s2l[pp * 128 + wr * 64 + m * 16 + ((lane >> 4) << 2)];
#pragma unroll
                for (int n = 0; n < 4; n++) {
                    accO[m][n] += sv * acc[m][n];
                    acc[m][n] = (f32x4){0.f, 0.f, 0.f, 0.f};
                }
            }
        }
    }
#undef STAGE
#undef MFMA_STEP

#pragma unroll
    for (int m = 0; m < 4; m++) {
#pragma unroll
        for (int reg = 0; reg < 4; reg++) {
            int r = row0 + wr * 64 + m * 16 + ((lane >> 4) << 2) + reg;
            if (r >= M) continue;
#pragma unroll
            for (int n = 0; n < 4; n++) {
                int c = wc * 64 + n * 16 + (lane & 15);
                C[(size_t)r * 256 + c] = accO[m][n][reg];
            }
        }
    }
}

// ---------------------------------------------------------------------------
extern "C" void kernel_launch(void* const* d_in, const int* in_sizes, int n_in,
                              void* d_out, int out_size, void* d_ws, size_t ws_size,
                              hipStream_t stream)
{
    const float* x   = (const float*)d_in[0];
    const float* Wq  = (const float*)d_in[1];
    const float* Wk  = (const float*)d_in[2];
    const float* Wv  = (const float*)d_in[3];
    const float* Whp = (const float*)d_in[4];
    const int* eidx  = (const int*)d_in[5];
    const int* etyp  = (const int*)d_in[6];
    const int* erow = eidx;
    const int* ecol = eidx + EE;
    float* out = (float*)d_out;

    char* p = (char*)d_ws;
    unsigned short* xb    = (unsigned short*)p; p += (size_t)NN * DD * 2;
    unsigned short* xT    = (unsigned short*)p; p += (size_t)DD * NPAD * 2;
    char*           regB  = p;                  p += (size_t)NN * 768 * 2;   // Gp then Ascat
    unsigned short* Gb    = (unsigned short*)p; p += (size_t)RR * 65536 * 2;
    unsigned short* M1    = (unsigned short*)p; p += (size_t)RR * 65536 * 2;
    unsigned short* Tm    = (unsigned short*)p; p += (size_t)RR * 65536 * 2;
    unsigned short* Bout  = (unsigned short*)p; p += (size_t)256 * 1536 * 2;
    unsigned short* Wqb   = (unsigned short*)p; p += (size_t)RR * 65536 * 2;
    unsigned short* Wkb   = (unsigned short*)p; p += (size_t)RR * 65536 * 2;
    unsigned short* Wvb   = (unsigned short*)p; p += (size_t)RR * 65536 * 2;
    unsigned short* WhpT  = (unsigned short*)p; p += 65536 * 2;
    unsigned short* wbf   = (unsigned short*)p; p += (size_t)RR * NPAD * 2;
    float*          xw    = (float*)p;          p += 768 * 4;
    float*          tv    = (float*)p;          p += 768 * 4;
    float*          s2g   = (float*)p;          p += (size_t)RR * NN * 4;
    int*            c_in  = (int*)p;            p += (size_t)RR * NN * 4;
    int*            c_out = (int*)p;            p += (size_t)RR * NN * 4;
    int*            nr    = (int*)p;            p += 4 * 4;
    int*            off   = (int*)p;            p += (size_t)(RR * NN + 4) * 4;
    int*            cur   = (int*)p;            p += (size_t)RR * NN * 4;
    int*            scol  = (int*)p;            p += (size_t)EE * 4;
    int*            bsum  = (int*)p;            p += SNB * 4;
    float*          Gp    = (float*)regB;       // 50.3 MB, dead before Ascat written
    unsigned short* Ascat = (unsigned short*)regB;

    hipFuncSetAttribute((const void*)gemm_big,
                        hipFuncAttributeMaxDynamicSharedMemorySize, 148992);

    hipMemsetAsync(c_in, 0, (size_t)(6 * NN + 4) * sizeof(int), stream);
    prep_tc<<<TBLK + WBLK + CBLK, 256, 0, stream>>>(
        x, Wq, Wk, Wv, Whp, xb, xT, Wqb, Wkb, Wvb, WhpT,
        erow, ecol, etyp, c_in, c_out, nr);
    prep2<<<SNB + 256 + (3 * NPAD + 255) / 256, 256, 0, stream>>>(
        c_out, bsum, xT, c_in, xw, wbf);
    scan_bot<<<SNB, 256, 0, stream>>>(c_out, bsum, off, cur);
    fill_kernel<<<(EE + 255) / 256, 256, 0, stream>>>(erow, ecol, etyp, cur, scol);

    // Pre-G weight products: M1_r = Wq_r @ Wk_r^T ; Bout cols 768+ = Whp^T @ Wv_r^T
    gemm_nt<0, 0><<<dim3(2, 2, 3), 256, 0, stream>>>(Wqb, 256, Wkb, 256, M1, 256, 256, 256,
                                                     65536, 65536, 65536);
    gemm_nt<0, 0><<<dim3(2, 2, 3), 256, 0, stream>>>(WhpT, 256, Wvb, 256, Bout + 768, 1536,
                                                     256, 256, 0, 65536, 256);

    g_kernel<<<dim3(2, 2, GS), 512, 0, stream>>>(xT, wbf, Gp);
    // Gp reduction + tv matvec in one launch
    gred_mv<<<768 + 192, 256, 0, stream>>>(Gp, Gb, M1, xw, tv);

    // T_r = M1_r @ G_r (G symmetric) ; Bout cols 0..767 = (M2T_r) @ T_r^T
    gemm_nt<0, 0><<<dim3(2, 2, 3), 256, 0, stream>>>(M1, 256, Gb, 256, Tm, 256, 256, 256,
                                                     65536, 65536, 65536);
    gemm_nt<0, 0><<<dim3(2, 2, 3), 256, 0, stream>>>(Bout + 768, 1536, Tm, 256, Bout, 1536,
                                                     256, 256, 256, 65536, 256);

    gather_kernel<<<(NN + 3) / 4, 256, 0, stream>>>(
        xb, scol, off, tv, c_out, nr, Ascat, s2g);

    const int MB2 = (NN + 127) / 128;  // 391
    gemm_big<<<dim3(MB2, 1), 512, 148992, stream>>>(xb, Ascat, Bout, s2g, out, NN);
}

// Round 16
// 288.608 us; speedup vs baseline: 1.1962x; 1.1962x over previous
//
#include <hip/hip_runtime.h>

#define NN 50000
#define EE 300000
#define DD 256
#define RR 3
#define NPAD 50048            // 782 * 64
#define GS 64                 // split-K slices for G
#define SCT (RR * NN)         // 150000
#define SCB 1024
#define SNB ((SCT + SCB - 1) / SCB)  // 147
#define TBLK 3128             // transpose blocks in prep_tc (782*4)
#define WBLK 2560             // weight-copy blocks in prep_tc
#define CBLK 512              // count blocks in prep_tc

using bf16x8 = __attribute__((ext_vector_type(8))) short;
using f32x4  = __attribute__((ext_vector_type(4))) float;

__device__ __forceinline__ float bf2f(unsigned short u) {
    return __uint_as_float(((unsigned)u) << 16);
}
__device__ __forceinline__ unsigned short f2bf(float f) {
    unsigned u = __float_as_uint(f);
    return (unsigned short)((u + 0x7fffu + ((u >> 16) & 1u)) >> 16);
}
__device__ __forceinline__ void gload_lds16(const void* g, void* l) {
    __builtin_amdgcn_global_load_lds(
        (const __attribute__((address_space(1))) unsigned int*)g,
        (__attribute__((address_space(3))) unsigned int*)l, 16, 0, 0);
}

// ---------------------------------------------------------------------------
// Merged: x transpose/convert + weight bf16 copies + degree counts.
__global__ __launch_bounds__(256) void prep_tc(
    const float* __restrict__ x, const float* __restrict__ Wq,
    const float* __restrict__ Wk, const float* __restrict__ Wv,
    const float* __restrict__ Whp,
    unsigned short* __restrict__ xb, unsigned short* __restrict__ xT,
    unsigned short* __restrict__ Wqb, unsigned short* __restrict__ Wkb,
    unsigned short* __restrict__ Wvb, unsigned short* __restrict__ WhpT,
    const int* __restrict__ erow, const int* __restrict__ ecol,
    const int* __restrict__ etype, int* __restrict__ c_in,
    int* __restrict__ c_out, int* __restrict__ nr)
{
    const int tid = threadIdx.x;
    if (blockIdx.x < TBLK) {
        __shared__ unsigned short t[64][66];
        const int tb = blockIdx.x;
        const int n0 = (tb % 782) * 64, i0 = (tb / 782) * 64;
        const int nl = tid >> 2, c0 = (tid & 3) * 16;
        unsigned short vb[16];
        int n = n0 + nl;
        if (n < NN) {
            const float* src = x + (size_t)n * DD + i0 + c0;
#pragma unroll
            for (int q = 0; q < 16; q += 4) {
                float4 v = *(const float4*)(src + q);
                vb[q] = f2bf(v.x); vb[q + 1] = f2bf(v.y);
                vb[q + 2] = f2bf(v.z); vb[q + 3] = f2bf(v.w);
            }
#pragma unroll
            for (int q = 0; q < 16; q += 4)
                *(ushort4*)(xb + (size_t)n * DD + i0 + c0 + q) =
                    make_ushort4(vb[q], vb[q + 1], vb[q + 2], vb[q + 3]);
        } else {
#pragma unroll
            for (int q = 0; q < 16; q++) vb[q] = 0;
        }
#pragma unroll
        for (int q = 0; q < 16; q++) t[nl][c0 + q] = vb[q];
        __syncthreads();
        const int il = tid >> 2, nc0 = (tid & 3) * 16;
        unsigned short ob[16];
#pragma unroll
        for (int q = 0; q < 16; q++) ob[q] = t[nc0 + q][il];
#pragma unroll
        for (int q = 0; q < 16; q += 4)
            *(ushort4*)(xT + (size_t)(i0 + il) * NPAD + n0 + nc0 + q) =
                make_ushort4(ob[q], ob[q + 1], ob[q + 2], ob[q + 3]);
    } else if (blockIdx.x < TBLK + WBLK) {
        int t = (blockIdx.x - TBLK) * 256 + tid;
        int slot = t >> 16, o = t & 65535;
        int a = o >> 8, b = o & 255;
        if (slot < 3)       Wqb[(size_t)slot * 65536 + o] = f2bf(Wq[(size_t)slot * 65536 + o]);
        else if (slot < 6)  Wkb[(size_t)(slot - 3) * 65536 + o] = f2bf(Wk[(size_t)(slot - 3) * 65536 + o]);
        else if (slot < 9)  Wvb[(size_t)(slot - 6) * 65536 + o] = f2bf(Wv[(size_t)(slot - 6) * 65536 + o]);
        else if (slot == 9) WhpT[o] = f2bf(Whp[b * 256 + a]);
    } else {
        __shared__ int lnr[RR];
        if (tid < RR) lnr[tid] = 0;
        __syncthreads();
        int cb = blockIdx.x - (TBLK + WBLK);
        for (int e = cb * 256 + tid; e < EE; e += CBLK * 256) {
            int t = etype[e];
            atomicAdd(&c_out[t * NN + erow[e]], 1);
            atomicAdd(&c_in[t * NN + ecol[e]], 1);
            atomicAdd(&lnr[t], 1);
        }
        __syncthreads();
        if (tid < RR) atomicAdd(&nr[tid], lnr[tid]);
    }
}

// ---------------------------------------------------------------------------
// Merged: blocks 0..SNB-1 scan_reduce; SNB..SNB+255 xw; rest wbf conversion.
__global__ __launch_bounds__(256) void prep2(
    const int* __restrict__ c_out, int* __restrict__ bsum,
    const unsigned short* __restrict__ xT, const int* __restrict__ c_in,
    float* __restrict__ xw, unsigned short* __restrict__ wbf)
{
    const int tid = threadIdx.x;
    if (blockIdx.x < SNB) {
        __shared__ int ws[4];
        const int b = blockIdx.x;
        const int i = b * SCB + tid * 4;
        int s = 0;
        if (i < SCT) {
            int4 v = *(const int4*)(c_out + i);
            s = v.x + v.y + v.z + v.w;
        }
#pragma unroll
        for (int off = 32; off; off >>= 1) s += __shfl_down(s, off, 64);
        if ((tid & 63) == 0) ws[tid >> 6] = s;
        __syncthreads();
        if (tid == 0) bsum[b] = ws[0] + ws[1] + ws[2] + ws[3];
    } else if (blockIdx.x < SNB + 256) {
        __shared__ float red[3][4];
        const int i = blockIdx.x - SNB;
        float a0 = 0.f, a1 = 0.f, a2 = 0.f;
        for (int n = tid * 4; n < NN; n += 1024) {
            ushort4 xv = *(const ushort4*)(xT + (size_t)i * NPAD + n);
            int4 w0 = *(const int4*)(c_in + n);
            int4 w1 = *(const int4*)(c_in + NN + n);
            int4 w2 = *(const int4*)(c_in + 2 * NN + n);
            float f0 = bf2f(xv.x), f1 = bf2f(xv.y), f2 = bf2f(xv.z), f3 = bf2f(xv.w);
            a0 += f0 * w0.x + f1 * w0.y + f2 * w0.z + f3 * w0.w;
            a1 += f0 * w1.x + f1 * w1.y + f2 * w1.z + f3 * w1.w;
            a2 += f0 * w2.x + f1 * w2.y + f2 * w2.z + f3 * w2.w;
        }
#pragma unroll
        for (int off = 32; off; off >>= 1) {
            a0 += __shfl_down(a0, off, 64);
            a1 += __shfl_down(a1, off, 64);
            a2 += __shfl_down(a2, off, 64);
        }
        if ((tid & 63) == 0) {
            red[0][tid >> 6] = a0; red[1][tid >> 6] = a1; red[2][tid >> 6] = a2;
        }
        __syncthreads();
        if (tid < 3)
            xw[tid * 256 + i] = red[tid][0] + red[tid][1] + red[tid][2] + red[tid][3];
    } else {
        int t = (blockIdx.x - SNB - 256) * 256 + tid;
        if (t < 3 * NPAD) {
            int r = t / NPAD, n = t % NPAD;
            wbf[t] = f2bf(n < NN ? (float)c_in[r * NN + n] : 0.f);
        }
    }
}

// ---------------------------------------------------------------------------
// scan_bot with top-scan absorbed: each block scans bsum locally.
__global__ __launch_bounds__(256) void scan_bot(
    const int* __restrict__ cnt, const int* __restrict__ bsum,
    int* __restrict__ off, int* __restrict__ cur)
{
    __shared__ int bs[256], loc[256];
    const int b = blockIdx.x, tid = threadIdx.x;
    int v = tid < SNB ? bsum[tid] : 0;
    bs[tid] = v;
    __syncthreads();
    for (int d = 1; d < 256; d <<= 1) {
        int t = (tid >= d) ? bs[tid - d] : 0;
        __syncthreads();
        bs[tid] += t;
        __syncthreads();
    }
    const int myboff = b ? bs[b - 1] : 0;
    const int total = bs[255];
    const int i = b * SCB + tid * 4;
    int4 vv = make_int4(0, 0, 0, 0);
    if (i < SCT) vv = *(const int4*)(cnt + i);
    int s = vv.x + vv.y + vv.z + vv.w;
    loc[tid] = s;
    __syncthreads();
    for (int d = 1; d < 256; d <<= 1) {
        int t = (tid >= d) ? loc[tid - d] : 0;
        __syncthreads();
        loc[tid] += t;
        __syncthreads();
    }
    if (i < SCT) {
        int pre = myboff + (tid ? loc[tid - 1] : 0);
        int4 o;
        o.x = pre;
        o.y = pre + vv.x;
        o.z = pre + vv.x + vv.y;
        o.w = pre + vv.x + vv.y + vv.z;
        *(int4*)(off + i) = o;
        *(int4*)(cur + i) = o;
    }
    if (b == 0 && tid == 0) off[SCT] = total;
}

// Bucket-fill: sorted_col grouped by key (t*NN+row).
__global__ __launch_bounds__(256) void fill_kernel(
    const int* __restrict__ erow, const int* __restrict__ ecol,
    const int* __restrict__ etype, int* __restrict__ cur,
    int* __restrict__ scol)
{
    int e = blockIdx.x * 256 + threadIdx.x;
    if (e < EE) {
        int key = etype[e] * NN + erow[e];
        int p = atomicAdd(&cur[key], 1);
        scol[p] = ecol[e];
    }
}

// ---------------------------------------------------------------------------
// G partials: Gp[z][tile][r][128*128] += xT(w-scaled) @ xT^T over node chunk z
__global__ __launch_bounds__(512) void g_kernel(
    const unsigned short* __restrict__ xT, const unsigned short* __restrict__ wbf,
    float* __restrict__ Gp)
{
    __shared__ __align__(16) char ldsA[16384];
    __shared__ __align__(16) char ldsB[16384];
    const int tid = threadIdx.x, lane = tid & 63, wid = tid >> 6;
    const int wr = wid >> 1, wc = wid & 1;
    const int i0 = blockIdx.x * 128, j0 = blockIdx.y * 128;
    const int TPZ = (NPAD / 64 + GS - 1) / GS;
    const int kt0 = blockIdx.z * TPZ;
    const int kt1 = min(NPAD / 64, kt0 + TPZ);

    f32x4 acc[3][2][4];
#pragma unroll
    for (int r = 0; r < 3; r++)
#pragma unroll
        for (int m = 0; m < 2; m++)
#pragma unroll
            for (int n = 0; n < 4; n++) acc[r][m][n] = (f32x4){0.f, 0.f, 0.f, 0.f};

    for (int kt = kt0; kt < kt1; kt++) {
        const int kbyte = kt * 128;
#pragma unroll
        for (int is = 0; is < 2; is++) {
            int lb = is * 8192 + wid * 1024;
            int d = lb + lane * 16;
            int row = d >> 7;
            int sc_ = (d & 127) ^ ((row & 7) << 4);
            gload_lds16((const char*)xT + (size_t)(i0 + row) * (NPAD * 2) + kbyte + sc_, ldsA + lb);
            gload_lds16((const char*)xT + (size_t)(j0 + row) * (NPAD * 2) + kbyte + sc_, ldsB + lb);
        }
        __syncthreads();
#pragma unroll
        for (int kk = 0; kk < 2; kk++) {
            const int cb = kk * 64 + ((lane >> 4) << 4);
            bf16x8 bfr[4];
#pragma unroll
            for (int n = 0; n < 4; n++) {
                int rn = wc * 64 + n * 16 + (lane & 15);
                bfr[n] = *(const bf16x8*)(ldsB + rn * 128 + (cb ^ ((rn & 7) << 4)));
            }
            float au[2][8];
#pragma unroll
            for (int m = 0; m < 2; m++) {
                int row = wr * 32 + m * 16 + (lane & 15);
                bf16x8 ar = *(const bf16x8*)(ldsA + row * 128 + (cb ^ ((row & 7) << 4)));
#pragma unroll
                for (int q = 0; q < 8; q++) au[m][q] = bf2f((unsigned short)ar[q]);
            }
            const int nb = kt * 64 + kk * 32 + ((lane >> 4) << 3);
#pragma unroll
            for (int r = 0; r < 3; r++) {
                bf16x8 wv = *(const bf16x8*)(wbf + (size_t)r * NPAD + nb);
                float wf[8];
#pragma unroll
                for (int q = 0; q < 8; q++) wf[q] = bf2f((unsigned short)wv[q]);
                bf16x8 am[2];
#pragma unroll
                for (int m = 0; m < 2; m++)
#pragma unroll
                    for (int q = 0; q < 8; q++)
                        am[m][q] = (short)f2bf(au[m][q] * wf[q]);
#pragma unroll
                for (int m = 0; m < 2; m++)
#pragma unroll
                    for (int n = 0; n < 4; n++)
                        acc[r][m][n] = __builtin_amdgcn_mfma_f32_16x16x32_bf16(
                            am[m], bfr[n], acc[r][m][n], 0, 0, 0);
            }
        }
        __syncthreads();
    }
    float* base = Gp + ((size_t)blockIdx.z * 4 + blockIdx.x * 2 + blockIdx.y) * 3 * 16384;
#pragma unroll
    for (int r = 0; r < 3; r++)
#pragma unroll
        for (int m = 0; m < 2; m++)
#pragma unroll
            for (int n = 0; n < 4; n++) {
                int col = wc * 64 + n * 16 + (lane & 15);
                int rw0 = wr * 32 + m * 16 + ((lane >> 4) << 2);
#pragma unroll
                for (int reg = 0; reg < 4; reg++)
                    base[r * 16384 + (rw0 + reg) * 128 + col] = acc[r][m][n][reg];
            }
}

// ---------------------------------------------------------------------------
// Merged: blocks 0..767 reduce Gp over z -> Gb (bf16);
//         blocks 768..959: tv[r][row] = dot(M1[r] row, xw[r])   (matvec)
__global__ __launch_bounds__(256) void gred_mv(
    const float* __restrict__ Gp, unsigned short* __restrict__ Gb,
    const unsigned short* __restrict__ M1, const float* __restrict__ xw,
    float* __restrict__ tv)
{
    const int tid = threadIdx.x;
    if (blockIdx.x < 768) {
        int gid = blockIdx.x * 256 + tid;
        int t = gid >> 14, rem = gid & 16383;
        int r = t % 3, tile = t / 3;
        float s = 0.f;
        for (int z = 0; z < GS; z++)
            s += Gp[(size_t)z * 196608 + ((size_t)tile * 3 + r) * 16384 + rem];
        int i = (tile >> 1) * 128 + (rem >> 7);
        int j = (tile & 1) * 128 + (rem & 127);
        Gb[(size_t)r * 65536 + i * 256 + j] = f2bf(s);
    } else {
        __shared__ float vs[256];
        const int b = blockIdx.x - 768;
        const int r = b >> 6, rb = (b & 63) * 4;
        vs[tid] = xw[r * 256 + tid];
        __syncthreads();
        const int wid = tid >> 6, lane = tid & 63;
        const int row = rb + wid;
        ushort4 m4 = *(const ushort4*)(M1 + (size_t)r * 65536 + row * 256 + lane * 4);
        float s = bf2f(m4.x) * vs[lane * 4] + bf2f(m4.y) * vs[lane * 4 + 1] +
                  bf2f(m4.z) * vs[lane * 4 + 2] + bf2f(m4.w) * vs[lane * 4 + 3];
#pragma unroll
        for (int off = 32; off; off >>= 1) s += __shfl_down(s, off, 64);
        if (lane == 0) tv[r * 256 + row] = s;
    }
}

// ---------------------------------------------------------------------------
// One wave per node, qs fused, interleaved 3-stream segment walk.
__global__ __launch_bounds__(256) void gather_kernel(
    const unsigned short* __restrict__ xb, const int* __restrict__ scol,
    const int* __restrict__ off, const float* __restrict__ tv,
    const int* __restrict__ c_out, const int* __restrict__ nr,
    unsigned short* __restrict__ Ascat, float* __restrict__ s2g)
{
    __shared__ float ts[768];
    __shared__ float nrs[RR];
    const int tid = threadIdx.x;
    for (int k = tid; k < 768; k += 256) ts[k] = tv[k];
    if (tid < RR) nrs[tid] = (float)nr[tid];
    __syncthreads();
    const int wid = tid >> 6, lane = tid & 63;
    const int n = blockIdx.x * 4 + wid;
    if (n >= NN) return;
    ushort4 xv = *(const ushort4*)(xb + (size_t)n * DD + lane * 4);
    float xf[4] = {bf2f(xv.x), bf2f(xv.y), bf2f(xv.z), bf2f(xv.w)};
    float dots[RR];
#pragma unroll
    for (int t = 0; t < RR; t++) {
        float s = xf[0] * ts[t * 256 + lane * 4] + xf[1] * ts[t * 256 + lane * 4 + 1] +
                  xf[2] * ts[t * 256 + lane * 4 + 2] + xf[3] * ts[t * 256 + lane * 4 + 3];
#pragma unroll
        for (int o = 32; o; o >>= 1) s += __shfl_xor(s, o, 64);
        dots[t] = s;
    }
    int i0 = off[0 * NN + n], e0 = off[0 * NN + n + 1];
    int i1 = off[1 * NN + n], e1 = off[1 * NN + n + 1];
    int i2 = off[2 * NN + n], e2 = off[2 * NN + n + 1];
    float a0[4] = {0.f, 0.f, 0.f, 0.f};
    float a1[4] = {0.f, 0.f, 0.f, 0.f};
    float a2[4] = {0.f, 0.f, 0.f, 0.f};
    while (i0 < e0 || i1 < e1 || i2 < e2) {
        bool h0 = i0 < e0, h1 = i1 < e1, h2 = i2 < e2;
        ushort4 v0, v1, v2;
        if (h0) { int c = scol[i0]; v0 = *(const ushort4*)(xb + (size_t)c * DD + lane * 4); }
        if (h1) { int c = scol[i1]; v1 = *(const ushort4*)(xb + (size_t)c * DD + lane * 4); }
        if (h2) { int c = scol[i2]; v2 = *(const ushort4*)(xb + (size_t)c * DD + lane * 4); }
        if (h0) { a0[0] += bf2f(v0.x); a0[1] += bf2f(v0.y);
                  a0[2] += bf2f(v0.z); a0[3] += bf2f(v0.w); i0++; }
        if (h1) { a1[0] += bf2f(v1.x); a1[1] += bf2f(v1.y);
                  a1[2] += bf2f(v1.z); a1[3] += bf2f(v1.w); i1++; }
        if (h2) { a2[0] += bf2f(v2.x); a2[1] += bf2f(v2.y);
                  a2[2] += bf2f(v2.z); a2[3] += bf2f(v2.w); i2++; }
    }
    float* accs[3] = {a0, a1, a2};
#pragma unroll
    for (int t = 0; t < RR; t++) {
        float nrf = nrs[t];
        float denom = dots[t] + nrf;
        if (lane == 0) {
            int cnt = c_out[t * NN + n];
            s2g[(size_t)t * NN + n] = cnt ? (float)cnt / denom : 0.f;
        }
        float s1 = nrf / denom;
        float* a = accs[t];
        ushort4 o2;
        o2.x = f2bf(s1 * a[0]); o2.y = f2bf(s1 * a[1]);
        o2.z = f2bf(s1 * a[2]); o2.w = f2bf(s1 * a[3]);
        *(ushort4*)(Ascat + (size_t)n * 768 + t * 256 + lane * 4) = o2;
    }
}

// ---------------------------------------------------------------------------
// Small MFMA NT GEMM (for 256x256 weight products)
template <int MODE, int SWZ>
__global__ __launch_bounds__(256) void gemm_nt(
    const unsigned short* __restrict__ A, int lda,
    const unsigned short* __restrict__ B, int ldb,
    void* __restrict__ Cv, int ldc, int M, int KK,
    size_t sa, size_t sb, size_t sc)
{
    A += (size_t)blockIdx.z * sa;
    B += (size_t)blockIdx.z * sb;
    __shared__ __align__(16) char ldsA[16384];
    __shared__ __align__(16) char ldsB[16384];
    const int tid = threadIdx.x, lane = tid & 63, wid = tid >> 6;
    const int wr = wid >> 1, wc = wid & 1;
    int bx = blockIdx.x;
    if (SWZ) {
        int nwg = gridDim.x, q = nwg >> 3, rem = nwg & 7;
        int xcd = bx & 7, idx = bx >> 3;
        bx = (xcd < rem ? xcd * (q + 1) : rem * (q + 1) + (xcd - rem) * q) + idx;
    }
    const int row0 = bx * 128, col0 = blockIdx.y * 128;

    f32x4 acc[4][4];
#pragma unroll
    for (int m = 0; m < 4; m++)
#pragma unroll
        for (int n = 0; n < 4; n++) acc[m][n] = (f32x4){0.f, 0.f, 0.f, 0.f};

    for (int k0 = 0; k0 < KK; k0 += 64) {
#pragma unroll
        for (int is = 0; is < 4; is++) {
            int lb = is * 4096 + wid * 1024;
            int d = lb + lane * 16;
            int row = d >> 7;
            int sc_ = (d & 127) ^ ((row & 7) << 4);
            int gr = row0 + row; gr = gr < M ? gr : M - 1;
            gload_lds16((const char*)(A + (size_t)gr * lda + k0) + sc_, ldsA + lb);
            int rn = col0 + row;
            gload_lds16((const char*)(B + (size_t)rn * ldb + k0) + sc_, ldsB + lb);
        }
        __syncthreads();
#pragma unroll
        for (int kk = 0; kk < 2; kk++) {
            bf16x8 af[4], bf_[4];
            const int cb = kk * 64 + ((lane >> 4) << 4);
#pragma unroll
            for (int m = 0; m < 4; m++) {
                int row = wr * 64 + m * 16 + (lane & 15);
                af[m] = *(const bf16x8*)(ldsA + row * 128 + (cb ^ ((row & 7) << 4)));
                int rn = wc * 64 + m * 16 + (lane & 15);
                bf_[m] = *(const bf16x8*)(ldsB + rn * 128 + (cb ^ ((rn & 7) << 4)));
            }
#pragma unroll
            for (int m = 0; m < 4; m++)
#pragma unroll
                for (int n = 0; n < 4; n++)
                    acc[m][n] = __builtin_amdgcn_mfma_f32_16x16x32_bf16(
                        af[m], bf_[n], acc[m][n], 0, 0, 0);
        }
        __syncthreads();
    }

#pragma unroll
    for (int m = 0; m < 4; m++) {
#pragma unroll
        for (int reg = 0; reg < 4; reg++) {
            int r = row0 + wr * 64 + m * 16 + ((lane >> 4) << 2) + reg;
            if (r >= M) continue;
#pragma unroll
            for (int n = 0; n < 4; n++) {
                int c = col0 + wc * 64 + n * 16 + (lane & 15);
                float v = acc[m][n][reg];
                if (MODE == 0)
                    ((unsigned short*)Cv)[(size_t)blockIdx.z * sc + (size_t)r * ldc + c] = f2bf(v);
                else
                    ((float*)Cv)[(size_t)blockIdx.z * sc + (size_t)r * ldc + c] = v;
            }
        }
    }
}

// ---------------------------------------------------------------------------
// Final fused GEMM (round-14 verified version): depth-1 prefetch, 2 LDS
// buffers, one __syncthreads() per K-step.
// out = Σ_r diag(s2_r)(xb@Bnum_r^T) + Ascat@Bsc^T
__global__ __launch_bounds__(512) void gemm_big(
    const unsigned short* __restrict__ Xb, const unsigned short* __restrict__ As,
    const unsigned short* __restrict__ Bm, const float* __restrict__ s2g,
    float* __restrict__ C, int M)
{
    extern __shared__ __align__(16) char lds[];
    char* ldsA = lds;              // 2 x 16384
    char* ldsB = lds + 32768;      // 2 x 32768
    float* s2l = (float*)(lds + 98304);  // 384 floats
    const int tid = threadIdx.x, lane = tid & 63, wid = tid >> 6;
    const int wr = wid >> 2, wc = wid & 3;
    int bx = blockIdx.x;
    {
        int nwg = gridDim.x, q = nwg >> 3, rem = nwg & 7;
        int xcd = bx & 7, idx = bx >> 3;
        bx = (xcd < rem ? xcd * (q + 1) : rem * (q + 1) + (xcd - rem) * q) + idx;
    }
    const int row0 = bx * 128;

    if (tid < 384) {
        int rsel = tid >> 7, rr = tid & 127;
        int gr = row0 + rr; gr = gr < M ? gr : M - 1;
        s2l[tid] = s2g[(size_t)rsel * NN + gr];
    }

    f32x4 accO[4][4], acc[4][4];
#pragma unroll
    for (int m = 0; m < 4; m++)
#pragma unroll
        for (int n = 0; n < 4; n++) {
            accO[m][n] = (f32x4){0.f, 0.f, 0.f, 0.f};
            acc[m][n]  = (f32x4){0.f, 0.f, 0.f, 0.f};
        }

#define STAGE_A(buf, Asrc, ldaE, kE)                                           \
    { _Pragma("unroll")                                                        \
      for (int is = 0; is < 2; is++) {                                         \
          int lb = is * 8192 + wid * 1024;                                     \
          int d = lb + lane * 16;                                              \
          int row = d >> 7;                                                    \
          int sc_ = (d & 127) ^ ((row & 7) << 4);                              \
          int gr = row0 + row; gr = gr < M ? gr : M - 1;                       \
          gload_lds16((const char*)((Asrc) + (size_t)gr * (ldaE) + (kE)) + sc_,\
                      ldsA + (buf) * 16384 + lb); } }

#define STAGE_B(buf, kE)                                                       \
    { _Pragma("unroll")                                                        \
      for (int is = 0; is < 4; is++) {                                         \
          int lb = is * 8192 + wid * 1024;                                     \
          int d = lb + lane * 16;                                              \
          int row = d >> 7;                                                    \
          int sc_ = (d & 127) ^ ((row & 7) << 4);                              \
          gload_lds16((const char*)(Bm + (size_t)row * 1536 + (kE)) + sc_,     \
                      ldsB + (buf) * 32768 + lb); } }

#define MFMA_STEP(abuf, bbuf, ACC)                                             \
    { const char* bA = ldsA + (abuf) * 16384;                                  \
      const char* bB = ldsB + (bbuf) * 32768;                                  \
      _Pragma("unroll")                                                        \
      for (int kk = 0; kk < 2; kk++) {                                         \
          bf16x8 af[4], bf_[4];                                                \
          const int cb = kk * 64 + ((lane >> 4) << 4);                         \
          _Pragma("unroll")                                                    \
          for (int m = 0; m < 4; m++) {                                        \
              int row = wr * 64 + m * 16 + (lane & 15);                        \
              af[m] = *(const bf16x8*)(bA + row * 128 + (cb ^ ((row & 7) << 4)));\
              int rn = wc * 64 + m * 16 + (lane & 15);                         \
              bf_[m] = *(const bf16x8*)(bB + rn * 128 + (cb ^ ((rn & 7) << 4)));\
          }                                                                    \
          _Pragma("unroll")                                                    \
          for (int m = 0; m < 4; m++)                                          \
              _Pragma("unroll")                                                \
              for (int n = 0; n < 4; n++)                                      \
                  ACC[m][n] = __builtin_amdgcn_mfma_f32_16x16x32_bf16(         \
                      af[m], bf_[n], ACC[m][n], 0, 0, 0); } }

    STAGE_A(0, Xb, 256, 0);
    STAGE_B(0, 0);
    __syncthreads();
    int ab = 0, bb = 0;

    for (int r = 0; r < 3; r++) {
        for (int kt = 0; kt < 4; kt++) {
            if (kt < 3)      { STAGE_A(ab ^ 1, Xb, 256, (kt + 1) * 64);
                               STAGE_B(bb ^ 1, r * 256 + (kt + 1) * 64); }
            else if (r < 2)  { STAGE_A(ab ^ 1, Xb, 256, 0);
                               STAGE_B(bb ^ 1, (r + 1) * 256); }
            else             { STAGE_A(ab ^ 1, As, 768, 0);
                               STAGE_B(bb ^ 1, 768); }
            MFMA_STEP(ab, bb, acc);
            __syncthreads();
            ab ^= 1; bb ^= 1;
        }
#pragma unroll
        for (int m = 0; m < 4; m++) {
            f32x4 sv = *(const f32x4*)&s2l[r * 128 + wr * 64 + m * 16 + ((lane >> 4) << 2)];
#pragma unroll
            for (int n = 0; n < 4; n++) {
                accO[m][n] += sv * acc[m][n];
                acc[m][n] = (f32x4){0.f, 0.f, 0.f, 0.f};
            }
        }
    }
    for (int st = 0; st < 12; st++) {
        if (st < 11) { STAGE_A(ab ^ 1, As, 768, (st + 1) * 64);
                       STAGE_B(bb ^ 1, 768 + (st + 1) * 64); }
        MFMA_STEP(ab, bb, accO);
        __syncthreads();
        ab ^= 1; bb ^= 1;
    }
#undef STAGE_A
#undef STAGE_B
#undef MFMA_STEP

#pragma unroll
    for (int m = 0; m < 4; m++) {
#pragma unroll
        for (int reg = 0; reg < 4; reg++) {
            int r = row0 + wr * 64 + m * 16 + ((lane >> 4) << 2) + reg;
            if (r >= M) continue;
#pragma unroll
            for (int n = 0; n < 4; n++) {
                int c = wc * 64 + n * 16 + (lane & 15);
                C[(size_t)r * 256 + c] = accO[m][n][reg];
            }
        }
    }
}

// ---------------------------------------------------------------------------
extern "C" void kernel_launch(void* const* d_in, const int* in_sizes, int n_in,
                              void* d_out, int out_size, void* d_ws, size_t ws_size,
                              hipStream_t stream)
{
    const float* x   = (const float*)d_in[0];
    const float* Wq  = (const float*)d_in[1];
    const float* Wk  = (const float*)d_in[2];
    const float* Wv  = (const float*)d_in[3];
    const float* Whp = (const float*)d_in[4];
    const int* eidx  = (const int*)d_in[5];
    const int* etyp  = (const int*)d_in[6];
    const int* erow = eidx;
    const int* ecol = eidx + EE;
    float* out = (float*)d_out;

    char* p = (char*)d_ws;
    unsigned short* xb    = (unsigned short*)p; p += (size_t)NN * DD * 2;
    unsigned short* xT    = (unsigned short*)p; p += (size_t)DD * NPAD * 2;
    char*           regB  = p;                  p += (size_t)NN * 768 * 2;   // Gp then Ascat
    unsigned short* Gb    = (unsigned short*)p; p += (size_t)RR * 65536 * 2;
    unsigned short* M1    = (unsigned short*)p; p += (size_t)RR * 65536 * 2;
    unsigned short* Tm    = (unsigned short*)p; p += (size_t)RR * 65536 * 2;
    unsigned short* Bout  = (unsigned short*)p; p += (size_t)256 * 1536 * 2;
    unsigned short* Wqb   = (unsigned short*)p; p += (size_t)RR * 65536 * 2;
    unsigned short* Wkb   = (unsigned short*)p; p += (size_t)RR * 65536 * 2;
    unsigned short* Wvb   = (unsigned short*)p; p += (size_t)RR * 65536 * 2;
    unsigned short* WhpT  = (unsigned short*)p; p += 65536 * 2;
    unsigned short* wbf   = (unsigned short*)p; p += (size_t)RR * NPAD * 2;
    float*          xw    = (float*)p;          p += 768 * 4;
    float*          tv    = (float*)p;          p += 768 * 4;
    float*          s2g   = (float*)p;          p += (size_t)RR * NN * 4;
    int*            c_in  = (int*)p;            p += (size_t)RR * NN * 4;
    int*            c_out = (int*)p;            p += (size_t)RR * NN * 4;
    int*            nr    = (int*)p;            p += 4 * 4;
    int*            off   = (int*)p;            p += (size_t)(RR * NN + 4) * 4;
    int*            cur   = (int*)p;            p += (size_t)RR * NN * 4;
    int*            scol  = (int*)p;            p += (size_t)EE * 4;
    int*            bsum  = (int*)p;            p += SNB * 4;
    float*          Gp    = (float*)regB;       // 50.3 MB, dead before Ascat written
    unsigned short* Ascat = (unsigned short*)regB;

    hipFuncSetAttribute((const void*)gemm_big,
                        hipFuncAttributeMaxDynamicSharedMemorySize, 99840);

    hipMemsetAsync(c_in, 0, (size_t)(6 * NN + 4) * sizeof(int), stream);
    prep_tc<<<TBLK + WBLK + CBLK, 256, 0, stream>>>(
        x, Wq, Wk, Wv, Whp, xb, xT, Wqb, Wkb, Wvb, WhpT,
        erow, ecol, etyp, c_in, c_out, nr);
    prep2<<<SNB + 256 + (3 * NPAD + 255) / 256, 256, 0, stream>>>(
        c_out, bsum, xT, c_in, xw, wbf);
    scan_bot<<<SNB, 256, 0, stream>>>(c_out, bsum, off, cur);
    fill_kernel<<<(EE + 255) / 256, 256, 0, stream>>>(erow, ecol, etyp, cur, scol);

    // Pre-G weight products: M1_r = Wq_r @ Wk_r^T ; Bout cols 768+ = Whp^T @ Wv_r^T
    gemm_nt<0, 0><<<dim3(2, 2, 3), 256, 0, stream>>>(Wqb, 256, Wkb, 256, M1, 256, 256, 256,
                                                     65536, 65536, 65536);
    gemm_nt<0, 0><<<dim3(2, 2, 3), 256, 0, stream>>>(WhpT, 256, Wvb, 256, Bout + 768, 1536,
                                                     256, 256, 0, 65536, 256);

    g_kernel<<<dim3(2, 2, GS), 512, 0, stream>>>(xT, wbf, Gp);
    // Gp reduction + tv matvec in one launch
    gred_mv<<<768 + 192, 256, 0, stream>>>(Gp, Gb, M1, xw, tv);

    // T_r = M1_r @ G_r (G symmetric) ; Bout cols 0..767 = (M2T_r) @ T_r^T
    gemm_nt<0, 0><<<dim3(2, 2, 3), 256, 0, stream>>>(M1, 256, Gb, 256, Tm, 256, 256, 256,
                                                     65536, 65536, 65536);
    gemm_nt<0, 0><<<dim3(2, 2, 3), 256, 0, stream>>>(Bout + 768, 1536, Tm, 256, Bout, 1536,
                                                     256, 256, 256, 65536, 256);

    gather_kernel<<<(NN + 3) / 4, 256, 0, stream>>>(
        xb, scol, off, tv, c_out, nr, Ascat, s2g);

    const int MB2 = (NN + 127) / 128;  // 391
    gemm_big<<<dim3(MB2, 1), 512, 99840, stream>>>(xb, Ascat, Bout, s2g, out, NN);
}